// Round 1
// baseline (76.493 us; speedup 1.0000x reference)
//
#include <hip/hip_runtime.h>
#include <hip/hip_bf16.h>

// Problem constants: B=2, C=64, H=64, W=64 -> N=8192 spatial positions, DH=32.
#define N_TOK   8192
#define DH      32
#define CCH     64
#define HWSZ    4096
#define LOG2E   1.4426950408889634f

typedef __attribute__((ext_vector_type(8))) short  bf16x8;
typedef __attribute__((ext_vector_type(4))) short  bf16x4;
typedef __attribute__((ext_vector_type(4))) float  f32x4;

static __device__ __forceinline__ short f2bf(float f) {
    __hip_bfloat16 h = __float2bfloat16(f);
    return __builtin_bit_cast(short, h);
}

// Load an A/B fragment for mfma_f32_16x16x32_bf16 from a row-major [rows][32]
// bf16 matrix: lane l supplies rows row0+(l&15), k = 8*(l>>4)..+8 (16B load).
static __device__ __forceinline__ bf16x8 load_frag8(const __hip_bfloat16* __restrict__ base,
                                                    int row0, int l) {
    const __hip_bfloat16* p = base + (size_t)(row0 + (l & 15)) * DH + ((l >> 4) << 3);
    return *reinterpret_cast<const bf16x8*>(p);
}

// ---------------------------------------------------------------------------
// K1: q/k/v projections. Thread = (n, d). Weights staged in LDS as
// [cgroup][d] float4 so ds_read_b128 is conflict-free. Q is pre-scaled by
// log2(e) so score kernels can use exp2 directly.
// ---------------------------------------------------------------------------
__global__ __launch_bounds__(256) void k_qkv(
        const float* __restrict__ x,
        const float* __restrict__ w1, const float* __restrict__ b1,
        const float* __restrict__ w2, const float* __restrict__ b2,
        const float* __restrict__ w3, const float* __restrict__ b3,
        __hip_bfloat16* __restrict__ Qb, __hip_bfloat16* __restrict__ Kb,
        float* __restrict__ V) {
    __shared__ float4 w1s[16][32];
    __shared__ float4 w2s[16][32];
    __shared__ float4 w3s[16][32];
    int t = threadIdx.x;
    for (int i = t; i < 512; i += 256) {
        int cg = i >> 5, d = i & 31;
        w1s[cg][d] = *reinterpret_cast<const float4*>(w1 + d * CCH + cg * 4);
        w2s[cg][d] = *reinterpret_cast<const float4*>(w2 + d * CCH + cg * 4);
        w3s[cg][d] = *reinterpret_cast<const float4*>(w3 + d * CCH + cg * 4);
    }
    __syncthreads();
    int d = t & 31;
    int n = blockIdx.x * 8 + (t >> 5);
    int b = n >> 12, hw = n & 4095;
    const float* xp = x + (size_t)b * (CCH * HWSZ) + hw;
    float aq = b1[d], ak = b2[d], av = b3[d];
    #pragma unroll
    for (int cg = 0; cg < 16; ++cg) {
        float x0 = xp[(cg * 4 + 0) * HWSZ];
        float x1 = xp[(cg * 4 + 1) * HWSZ];
        float x2 = xp[(cg * 4 + 2) * HWSZ];
        float x3 = xp[(cg * 4 + 3) * HWSZ];
        float4 a = w1s[cg][d];
        aq = fmaf(a.x, x0, aq); aq = fmaf(a.y, x1, aq);
        aq = fmaf(a.z, x2, aq); aq = fmaf(a.w, x3, aq);
        float4 bb = w2s[cg][d];
        ak = fmaf(bb.x, x0, ak); ak = fmaf(bb.y, x1, ak);
        ak = fmaf(bb.z, x2, ak); ak = fmaf(bb.w, x3, ak);
        float4 cc = w3s[cg][d];
        av = fmaf(cc.x, x0, av); av = fmaf(cc.y, x1, av);
        av = fmaf(cc.z, x2, av); av = fmaf(cc.w, x3, av);
    }
    Qb[(size_t)n * DH + d] = __float2bfloat16(aq * LOG2E);
    Kb[(size_t)n * DH + d] = __float2bfloat16(ak);
    V [(size_t)n * DH + d] = av;
}

// ---------------------------------------------------------------------------
// K2 (pass A): Zpart[ic][j] = sum_{i in chunk ic} exp(q_i . k_j).
// Wave handles a 64-column j-tile (4 K fragments, loaded once) and one
// i-chunk. S^T tiles via mfma(K, Q): lane holds rows j=(l>>4)*4+r,
// col i=l&15; Z reduction over i = shfl_xor over the 16-lane group.
// ---------------------------------------------------------------------------
__global__ __launch_bounds__(256) void k_zpart(
        const __hip_bfloat16* __restrict__ Qb, const __hip_bfloat16* __restrict__ Kb,
        float* __restrict__ Zpart, int nch) {
    int l  = threadIdx.x & 63;
    int gw = blockIdx.x * 4 + (threadIdx.x >> 6);
    int jt = gw / nch, ic = gw - jt * nch;
    int j0 = jt * 64;
    int ilen = N_TOK / nch;
    int i0 = ic * ilen;
    bf16x8 ka[4];
    #pragma unroll
    for (int f = 0; f < 4; ++f) ka[f] = load_frag8(Kb, j0 + f * 16, l);
    float zac[16];
    #pragma unroll
    for (int t = 0; t < 16; ++t) zac[t] = 0.f;
    const f32x4 z4 = {0.f, 0.f, 0.f, 0.f};
    #pragma unroll 2
    for (int i = i0; i < i0 + ilen; i += 16) {
        bf16x8 qf = load_frag8(Qb, i, l);
        #pragma unroll
        for (int f = 0; f < 4; ++f) {
            f32x4 s = __builtin_amdgcn_mfma_f32_16x16x32_bf16(ka[f], qf, z4, 0, 0, 0);
            #pragma unroll
            for (int r = 0; r < 4; ++r)
                zac[f * 4 + r] += __builtin_amdgcn_exp2f(s[r]);
        }
    }
    #pragma unroll
    for (int t = 0; t < 16; ++t) {
        float z = zac[t];
        z += __shfl_xor(z, 1); z += __shfl_xor(z, 2);
        z += __shfl_xor(z, 4); z += __shfl_xor(z, 8);
        zac[t] = z;
    }
    if ((l & 15) == 0) {
        int jr = (l >> 4) * 4;
        #pragma unroll
        for (int f = 0; f < 4; ++f)
            #pragma unroll
            for (int r = 0; r < 4; ++r)
                Zpart[(size_t)ic * N_TOK + j0 + f * 16 + jr + r] = zac[f * 4 + r];
    }
}

// ---------------------------------------------------------------------------
// K3: finalize Z and build v' = v / Z, stored transposed [DH][N] bf16.
// ---------------------------------------------------------------------------
__global__ __launch_bounds__(256) void k_zfin(
        const float* __restrict__ Zpart, const float* __restrict__ V,
        __hip_bfloat16* __restrict__ vpT, int nch) {
    int g = blockIdx.x * 256 + threadIdx.x;   // 262144 threads
    int d = g >> 13, n = g & (N_TOK - 1);
    float z = 0.f;
    for (int c = 0; c < nch; ++c) z += Zpart[(size_t)c * N_TOK + n];
    vpT[(size_t)d * N_TOK + n] = __float2bfloat16(V[(size_t)n * DH + d] * (1.f / z));
}

// ---------------------------------------------------------------------------
// K4 (pass B): oT[d][i] += sum_j exp(s_ij) * v'[j][d] for one i-tile (128
// rows, 8 Q fragments held in registers) x one j-chunk. The exp(S^T) D-frag
// (4 rows/lane) is bit-for-bit the B-operand layout of
// mfma_f32_16x16x16_bf16 (4 k/lane) -> PV needs no shuffles/LDS.
// ---------------------------------------------------------------------------
__global__ __launch_bounds__(256) void k_attn(
        const __hip_bfloat16* __restrict__ Qb, const __hip_bfloat16* __restrict__ Kb,
        const __hip_bfloat16* __restrict__ vpT, float* __restrict__ oTpart, int nch) {
    int l  = threadIdx.x & 63;
    int gw = blockIdx.x * 4 + (threadIdx.x >> 6);
    int it = gw / nch, jc = gw - it * nch;
    int i0 = it * 128;
    int jlen = N_TOK / nch;
    int j0c = jc * jlen;
    bf16x8 qb[8];
    #pragma unroll
    for (int f = 0; f < 8; ++f) qb[f] = load_frag8(Qb, i0 + f * 16, l);
    f32x4 acc0[8], acc1[8];
    #pragma unroll
    for (int f = 0; f < 8; ++f) { acc0[f] = {0.f,0.f,0.f,0.f}; acc1[f] = {0.f,0.f,0.f,0.f}; }
    const f32x4 z4 = {0.f, 0.f, 0.f, 0.f};
    int lo16 = l & 15, hi4 = (l >> 4) << 2;
    #pragma unroll 2
    for (int j = j0c; j < j0c + jlen; j += 16) {
        bf16x8 kaf = load_frag8(Kb, j, l);
        bf16x4 va0 = *reinterpret_cast<const bf16x4*>(vpT + (size_t)(lo16)      * N_TOK + j + hi4);
        bf16x4 va1 = *reinterpret_cast<const bf16x4*>(vpT + (size_t)(lo16 + 16) * N_TOK + j + hi4);
        #pragma unroll
        for (int f = 0; f < 8; ++f) {
            f32x4 s = __builtin_amdgcn_mfma_f32_16x16x32_bf16(kaf, qb[f], z4, 0, 0, 0);
            bf16x4 e;
            #pragma unroll
            for (int r = 0; r < 4; ++r) e[r] = f2bf(__builtin_amdgcn_exp2f(s[r]));
            acc0[f] = __builtin_amdgcn_mfma_f32_16x16x16bf16_1k(va0, e, acc0[f], 0, 0, 0);
            acc1[f] = __builtin_amdgcn_mfma_f32_16x16x16bf16_1k(va1, e, acc1[f], 0, 0, 0);
        }
    }
    int icol = i0 + lo16;
    #pragma unroll
    for (int f = 0; f < 8; ++f) {
        #pragma unroll
        for (int r = 0; r < 4; ++r) {
            oTpart[(size_t)(jc * DH + hi4 + r)      * N_TOK + icol + f * 16] = acc0[f][r];
            oTpart[(size_t)(jc * DH + 16 + hi4 + r) * N_TOK + icol + f * 16] = acc1[f][r];
        }
    }
}

// ---------------------------------------------------------------------------
// K5: reduce oT partials over j-chunks.
// ---------------------------------------------------------------------------
__global__ __launch_bounds__(256) void k_ored(
        const float* __restrict__ oTpart, float* __restrict__ oT, int nch) {
    int g = blockIdx.x * 256 + threadIdx.x;   // 262144
    float s = 0.f;
    for (int c = 0; c < nch; ++c) s += oTpart[(size_t)c * (DH * N_TOK) + g];
    oT[g] = s;
}

// ---------------------------------------------------------------------------
// K6: y = conv4(o) + b4 + x. Thread per output element; oT[d][n] reads are
// coalesced, w4/b4 are wave-uniform (scalar loads).
// ---------------------------------------------------------------------------
__global__ __launch_bounds__(256) void k_out(
        const float* __restrict__ oT, const float* __restrict__ w4,
        const float* __restrict__ b4, const float* __restrict__ x,
        float* __restrict__ y) {
    int idx = blockIdx.x * 256 + threadIdx.x;  // 524288
    int hw = idx & 4095;
    int c  = (idx >> 12) & 63;
    int b  = idx >> 18;
    int n  = b * HWSZ + hw;
    float acc = b4[c];
    #pragma unroll
    for (int d = 0; d < DH; ++d)
        acc = fmaf(w4[c * DH + d], oT[(size_t)d * N_TOK + n], acc);
    y[idx] = acc + x[idx];
}

extern "C" void kernel_launch(void* const* d_in, const int* in_sizes, int n_in,
                              void* d_out, int out_size, void* d_ws, size_t ws_size,
                              hipStream_t stream) {
    const float* x  = (const float*)d_in[0];
    const float* w1 = (const float*)d_in[1];
    const float* b1 = (const float*)d_in[2];
    const float* w2 = (const float*)d_in[3];
    const float* b2 = (const float*)d_in[4];
    const float* w3 = (const float*)d_in[5];
    const float* b3 = (const float*)d_in[6];
    const float* w4 = (const float*)d_in[7];
    const float* b4 = (const float*)d_in[8];
    float* y = (float*)d_out;

    char* ws = (char*)d_ws;
    const size_t MB = 1024 * 1024;
    __hip_bfloat16* Qb  = (__hip_bfloat16*)(ws + 0);             // 512 KB
    __hip_bfloat16* Kb  = (__hip_bfloat16*)(ws + 512 * 1024);    // 512 KB
    float*          V   = (float*)(ws + 1 * MB);                 // 1 MB
    __hip_bfloat16* vpT = (__hip_bfloat16*)(ws + 2 * MB);        // 512 KB
    float*          oT  = (float*)(ws + 2 * MB + 512 * 1024);    // 1 MB
    float*          Zp  = (float*)(ws + 3 * MB + 512 * 1024);    // <= 512 KB
    float*          oTp = (float*)(ws + 4 * MB);                 // nch MB

    int nch = 16;
    while (nch > 1 && (4 * MB + (size_t)nch * (MB + 32 * 1024)) > ws_size) nch >>= 1;

    hipLaunchKernelGGL(k_qkv,   dim3(1024),     dim3(256), 0, stream,
                       x, w1, b1, w2, b2, w3, b3, Qb, Kb, V);
    hipLaunchKernelGGL(k_zpart, dim3(32 * nch), dim3(256), 0, stream, Qb, Kb, Zp, nch);
    hipLaunchKernelGGL(k_zfin,  dim3(1024),     dim3(256), 0, stream, Zp, V, vpT, nch);
    hipLaunchKernelGGL(k_attn,  dim3(16 * nch), dim3(256), 0, stream, Qb, Kb, vpT, oTp, nch);
    hipLaunchKernelGGL(k_ored,  dim3(1024),     dim3(256), 0, stream, oTp, oT, nch);
    hipLaunchKernelGGL(k_out,   dim3(2048),     dim3(256), 0, stream, oT, w4, b4, x, y);
}

// Round 3
// 68.603 us; speedup vs baseline: 1.1150x; 1.1150x over previous
//
#include <hip/hip_runtime.h>
#include <hip/hip_bf16.h>

// Problem constants: B=2, C=64, H=64, W=64 -> N=8192 tokens, DH=32.
#define N_TOK   8192
#define DH      32
#define CCH     64
#define HWSZ    4096
#define LOG2E   1.4426950408889634f
#define NCH_Z   64     // i-chunks for Z pass: 128 j-tiles x 64 = 8192 waves (8/SIMD)
#define NCH_O   32     // j-chunks for PV pass: 128 i-tiles x 32 = 4096 waves (4/SIMD)
#define ITILE   64     // i-rows per wave in PV pass (4 Q fragments)

typedef __attribute__((ext_vector_type(8))) short  bf16x8;
typedef __attribute__((ext_vector_type(4))) short  bf16x4;
typedef __attribute__((ext_vector_type(4))) float  f32x4;

// Bit-pattern f32 -> bf16 short (for MFMA operand vectors ONLY — never assign
// the result to a __hip_bfloat16, that would value-convert the integer!).
static __device__ __forceinline__ short f2bf(float f) {
    __hip_bfloat16 h = __float2bfloat16(f);
    return __builtin_bit_cast(short, h);
}
static __device__ __forceinline__ float bf2f(short s) {
    unsigned u = ((unsigned)(unsigned short)s) << 16;
    return __builtin_bit_cast(float, u);
}

// A/B fragment for mfma_f32_16x16x32_bf16 from row-major [rows][32] bf16:
// lane l supplies row row0+(l&15), k = 8*(l>>4)..+8 (16B load).
static __device__ __forceinline__ bf16x8 load_frag8(const __hip_bfloat16* __restrict__ base,
                                                    int row0, int l) {
    const __hip_bfloat16* p = base + (size_t)(row0 + (l & 15)) * DH + ((l >> 4) << 3);
    return *reinterpret_cast<const bf16x8*>(p);
}

// ---------------------------------------------------------------------------
// K1: q/k/v projections. Weights in LDS as [cgroup][d] float4. Q pre-scaled
// by log2(e) so score kernels use a single v_exp_f32 (exp2) per element.
// ---------------------------------------------------------------------------
__global__ __launch_bounds__(256) void k_qkv(
        const float* __restrict__ x,
        const float* __restrict__ w1, const float* __restrict__ b1,
        const float* __restrict__ w2, const float* __restrict__ b2,
        const float* __restrict__ w3, const float* __restrict__ b3,
        __hip_bfloat16* __restrict__ Qb, __hip_bfloat16* __restrict__ Kb,
        float* __restrict__ V) {
    __shared__ float4 w1s[16][32];
    __shared__ float4 w2s[16][32];
    __shared__ float4 w3s[16][32];
    int t = threadIdx.x;
    for (int i = t; i < 512; i += 256) {
        int cg = i >> 5, d = i & 31;
        w1s[cg][d] = *reinterpret_cast<const float4*>(w1 + d * CCH + cg * 4);
        w2s[cg][d] = *reinterpret_cast<const float4*>(w2 + d * CCH + cg * 4);
        w3s[cg][d] = *reinterpret_cast<const float4*>(w3 + d * CCH + cg * 4);
    }
    __syncthreads();
    int d = t & 31;
    int n = blockIdx.x * 8 + (t >> 5);
    int b = n >> 12, hw = n & 4095;
    const float* xp = x + (size_t)b * (CCH * HWSZ) + hw;
    float aq = b1[d], ak = b2[d], av = b3[d];
    #pragma unroll
    for (int cg = 0; cg < 16; ++cg) {
        float x0 = xp[(cg * 4 + 0) * HWSZ];
        float x1 = xp[(cg * 4 + 1) * HWSZ];
        float x2 = xp[(cg * 4 + 2) * HWSZ];
        float x3 = xp[(cg * 4 + 3) * HWSZ];
        float4 a = w1s[cg][d];
        aq = fmaf(a.x, x0, aq); aq = fmaf(a.y, x1, aq);
        aq = fmaf(a.z, x2, aq); aq = fmaf(a.w, x3, aq);
        float4 bb = w2s[cg][d];
        ak = fmaf(bb.x, x0, ak); ak = fmaf(bb.y, x1, ak);
        ak = fmaf(bb.z, x2, ak); ak = fmaf(bb.w, x3, ak);
        float4 cc = w3s[cg][d];
        av = fmaf(cc.x, x0, av); av = fmaf(cc.y, x1, av);
        av = fmaf(cc.z, x2, av); av = fmaf(cc.w, x3, av);
    }
    Qb[(size_t)n * DH + d] = __float2bfloat16(aq * LOG2E);
    Kb[(size_t)n * DH + d] = __float2bfloat16(ak);
    V [(size_t)n * DH + d] = av;
}

// ---------------------------------------------------------------------------
// K2 (pass A): Zpart[ic][j] = sum_{i in chunk ic} exp2(q~_i . k_j).
// Wave: 64-col j-tile (4 K frags) x one i-chunk of 128 rows. 8192 waves.
// ---------------------------------------------------------------------------
__global__ __launch_bounds__(256) void k_zpart(
        const __hip_bfloat16* __restrict__ Qb, const __hip_bfloat16* __restrict__ Kb,
        float* __restrict__ Zpart) {
    int l  = threadIdx.x & 63;
    int gw = blockIdx.x * 4 + (threadIdx.x >> 6);
    int jt = gw / NCH_Z, ic = gw - jt * NCH_Z;
    int j0 = jt * 64;
    const int ilen = N_TOK / NCH_Z;          // 128
    int i0 = ic * ilen;
    bf16x8 ka[4];
    #pragma unroll
    for (int f = 0; f < 4; ++f) ka[f] = load_frag8(Kb, j0 + f * 16, l);
    float zac[16];
    #pragma unroll
    for (int t = 0; t < 16; ++t) zac[t] = 0.f;
    const f32x4 z4 = {0.f, 0.f, 0.f, 0.f};
    #pragma unroll 2
    for (int i = i0; i < i0 + ilen; i += 16) {
        bf16x8 qf = load_frag8(Qb, i, l);
        #pragma unroll
        for (int f = 0; f < 4; ++f) {
            f32x4 s = __builtin_amdgcn_mfma_f32_16x16x32_bf16(ka[f], qf, z4, 0, 0, 0);
            #pragma unroll
            for (int r = 0; r < 4; ++r)
                zac[f * 4 + r] += __builtin_amdgcn_exp2f(s[r]);
        }
    }
    #pragma unroll
    for (int t = 0; t < 16; ++t) {
        float z = zac[t];
        z += __shfl_xor(z, 1); z += __shfl_xor(z, 2);
        z += __shfl_xor(z, 4); z += __shfl_xor(z, 8);
        zac[t] = z;
    }
    if ((l & 15) == 0) {
        int jr = (l >> 4) * 4;
        #pragma unroll
        for (int f = 0; f < 4; ++f)
            #pragma unroll
            for (int r = 0; r < 4; ++r)
                Zpart[(size_t)ic * N_TOK + j0 + f * 16 + jr + r] = zac[f * 4 + r];
    }
}

// ---------------------------------------------------------------------------
// K3: thread-per-n: Z[n] = sum_c Zpart[c][n]; vpT[d][n] = v[n][d]/Z[n] (bf16).
// ---------------------------------------------------------------------------
__global__ __launch_bounds__(256) void k_zfin(
        const float* __restrict__ Zpart, const float* __restrict__ V,
        __hip_bfloat16* __restrict__ vpT) {
    int n = blockIdx.x * 256 + threadIdx.x;   // 8192 threads
    float z = 0.f;
    #pragma unroll 8
    for (int c = 0; c < NCH_Z; ++c) z += Zpart[(size_t)c * N_TOK + n];
    float zi = 1.f / z;
    const float4* vp = reinterpret_cast<const float4*>(V + (size_t)n * DH);
    #pragma unroll
    for (int g = 0; g < 8; ++g) {
        float4 v4 = vp[g];
        vpT[(size_t)(g * 4 + 0) * N_TOK + n] = __float2bfloat16(v4.x * zi);
        vpT[(size_t)(g * 4 + 1) * N_TOK + n] = __float2bfloat16(v4.y * zi);
        vpT[(size_t)(g * 4 + 2) * N_TOK + n] = __float2bfloat16(v4.z * zi);
        vpT[(size_t)(g * 4 + 3) * N_TOK + n] = __float2bfloat16(v4.w * zi);
    }
}

// ---------------------------------------------------------------------------
// K4 (pass B): oTpart[jc][d][i] = sum_{j in chunk jc} exp2(s~_ij) v'[j][d].
// Wave: 64-row i-tile (4 Q frags in regs) x 256-col j-chunk. 4096 waves.
// exp(S^T) D-frag (4 rows/lane) == B-operand layout of mfma_16x16x16_bf16.
// ---------------------------------------------------------------------------
__global__ __launch_bounds__(256) void k_attn(
        const __hip_bfloat16* __restrict__ Qb, const __hip_bfloat16* __restrict__ Kb,
        const __hip_bfloat16* __restrict__ vpT, __hip_bfloat16* __restrict__ oTpart) {
    int l  = threadIdx.x & 63;
    int gw = blockIdx.x * 4 + (threadIdx.x >> 6);
    int it = gw / NCH_O, jc = gw - it * NCH_O;
    int i0 = it * ITILE;
    const int jlen = N_TOK / NCH_O;           // 256
    int j0c = jc * jlen;
    bf16x8 qb[4];
    #pragma unroll
    for (int f = 0; f < 4; ++f) qb[f] = load_frag8(Qb, i0 + f * 16, l);
    f32x4 acc0[4], acc1[4];
    #pragma unroll
    for (int f = 0; f < 4; ++f) { acc0[f] = {0.f,0.f,0.f,0.f}; acc1[f] = {0.f,0.f,0.f,0.f}; }
    const f32x4 z4 = {0.f, 0.f, 0.f, 0.f};
    int lo16 = l & 15, hi4 = (l >> 4) << 2;
    #pragma unroll 2
    for (int j = j0c; j < j0c + jlen; j += 16) {
        bf16x8 kaf = load_frag8(Kb, j, l);
        bf16x4 va0 = *reinterpret_cast<const bf16x4*>(vpT + (size_t)(lo16)      * N_TOK + j + hi4);
        bf16x4 va1 = *reinterpret_cast<const bf16x4*>(vpT + (size_t)(lo16 + 16) * N_TOK + j + hi4);
        #pragma unroll
        for (int f = 0; f < 4; ++f) {
            f32x4 s = __builtin_amdgcn_mfma_f32_16x16x32_bf16(kaf, qb[f], z4, 0, 0, 0);
            bf16x4 e;
            #pragma unroll
            for (int r = 0; r < 4; ++r) e[r] = f2bf(__builtin_amdgcn_exp2f(s[r]));
            acc0[f] = __builtin_amdgcn_mfma_f32_16x16x16bf16_1k(va0, e, acc0[f], 0, 0, 0);
            acc1[f] = __builtin_amdgcn_mfma_f32_16x16x16bf16_1k(va1, e, acc1[f], 0, 0, 0);
        }
    }
    int icol = i0 + lo16;
    // NOTE: __float2bfloat16 (value conversion), NOT f2bf (bit pattern) —
    // assigning a short to __hip_bfloat16 would value-convert the integer.
    #pragma unroll
    for (int f = 0; f < 4; ++f) {
        #pragma unroll
        for (int r = 0; r < 4; ++r) {
            oTpart[(size_t)(jc * DH + hi4 + r)      * N_TOK + icol + f * 16] =
                __float2bfloat16(acc0[f][r]);
            oTpart[(size_t)(jc * DH + 16 + hi4 + r) * N_TOK + icol + f * 16] =
                __float2bfloat16(acc1[f][r]);
        }
    }
}

// ---------------------------------------------------------------------------
// K5: reduce bf16 oT partials over j-chunks (vectorized bf16x8 loads).
// ---------------------------------------------------------------------------
__global__ __launch_bounds__(256) void k_ored(
        const __hip_bfloat16* __restrict__ oTpart, float* __restrict__ oT) {
    int g = blockIdx.x * 256 + threadIdx.x;   // 32768 threads, 8 floats each
    size_t off = (size_t)g * 8;
    float s[8];
    #pragma unroll
    for (int k = 0; k < 8; ++k) s[k] = 0.f;
    #pragma unroll 4
    for (int c = 0; c < NCH_O; ++c) {
        bf16x8 v = *reinterpret_cast<const bf16x8*>(oTpart + (size_t)c * (DH * N_TOK) + off);
        #pragma unroll
        for (int k = 0; k < 8; ++k) s[k] += bf2f(v[k]);
    }
    float4* op = reinterpret_cast<float4*>(oT + off);
    op[0] = {s[0], s[1], s[2], s[3]};
    op[1] = {s[4], s[5], s[6], s[7]};
}

// ---------------------------------------------------------------------------
// K6: y = conv4(o) + b4 + x (thread per output element).
// ---------------------------------------------------------------------------
__global__ __launch_bounds__(256) void k_out(
        const float* __restrict__ oT, const float* __restrict__ w4,
        const float* __restrict__ b4, const float* __restrict__ x,
        float* __restrict__ y) {
    int idx = blockIdx.x * 256 + threadIdx.x;  // 524288
    int hw = idx & 4095;
    int c  = (idx >> 12) & 63;
    int b  = idx >> 18;
    int n  = b * HWSZ + hw;
    float acc = b4[c];
    #pragma unroll
    for (int d = 0; d < DH; ++d)
        acc = fmaf(w4[c * DH + d], oT[(size_t)d * N_TOK + n], acc);
    y[idx] = acc + x[idx];
}

extern "C" void kernel_launch(void* const* d_in, const int* in_sizes, int n_in,
                              void* d_out, int out_size, void* d_ws, size_t ws_size,
                              hipStream_t stream) {
    const float* x  = (const float*)d_in[0];
    const float* w1 = (const float*)d_in[1];
    const float* b1 = (const float*)d_in[2];
    const float* w2 = (const float*)d_in[3];
    const float* b2 = (const float*)d_in[4];
    const float* w3 = (const float*)d_in[5];
    const float* b3 = (const float*)d_in[6];
    const float* w4 = (const float*)d_in[7];
    const float* b4 = (const float*)d_in[8];
    float* y = (float*)d_out;

    char* ws = (char*)d_ws;
    const size_t KB = 1024;
    __hip_bfloat16* Qb  = (__hip_bfloat16*)(ws);                  // 512 KB
    __hip_bfloat16* Kb  = (__hip_bfloat16*)(ws + 512 * KB);       // 512 KB
    float*          V   = (float*)(ws + 1024 * KB);               // 1 MB
    __hip_bfloat16* vpT = (__hip_bfloat16*)(ws + 2048 * KB);      // 512 KB
    float*          oT  = (float*)(ws + 2560 * KB);               // 1 MB
    float*          Zp  = (float*)(ws + 3584 * KB);               // 2 MB (64 x 8192 f32)
    __hip_bfloat16* oTp = (__hip_bfloat16*)(ws + 5632 * KB);      // 16 MB (32 x 512KB)

    hipLaunchKernelGGL(k_qkv,   dim3(1024), dim3(256), 0, stream,
                       x, w1, b1, w2, b2, w3, b3, Qb, Kb, V);
    hipLaunchKernelGGL(k_zpart, dim3(128 * NCH_Z / 4), dim3(256), 0, stream, Qb, Kb, Zp);
    hipLaunchKernelGGL(k_zfin,  dim3(32),   dim3(256), 0, stream, Zp, V, vpT);
    hipLaunchKernelGGL(k_attn,  dim3((N_TOK / ITILE) * NCH_O / 4), dim3(256), 0, stream,
                       Qb, Kb, vpT, oTp);
    hipLaunchKernelGGL(k_ored,  dim3(128),  dim3(256), 0, stream, oTp, oT);
    hipLaunchKernelGGL(k_out,   dim3(2048), dim3(256), 0, stream, oT, w4, b4, x, y);
}